// Round 4
// baseline (217.497 us; speedup 1.0000x reference)
//
#include <hip/hip_runtime.h>

#define T_TOK  16384
#define IN_F   1024
#define OUT_F  1024
#define NE     8
#define BM     128
#define BN     128
#define BK     32
#define NTHREADS 256
#define ROW_TILE_SLOTS 136   // max sum of ceil(len_e/128) = 128 + 8

typedef __bf16 bf16;
typedef bf16  bf16x4 __attribute__((ext_vector_type(4)));
typedef bf16  bf16x8 __attribute__((ext_vector_type(8)));
typedef float f32x4  __attribute__((ext_vector_type(4)));

#define NX_ELEM ((size_t)T_TOK * IN_F)          // 16,777,216
#define NW_ELEM ((size_t)NE * OUT_F * IN_F)     // 8,388,608
#define WS_NEED ((NX_ELEM + NW_ELEM) * sizeof(bf16))   // ~48 MB

// ---------------- Phase 1: fp32 -> bf16 conversion into workspace ----------
__global__ __launch_bounds__(NTHREADS)
void cvt_to_bf16(const float* __restrict__ x, const float* __restrict__ w,
                 bf16* __restrict__ xb, bf16* __restrict__ wb)
{
    const size_t NX8 = NX_ELEM / 8;   // groups of 8 floats
    const size_t NW8 = NW_ELEM / 8;
    size_t stride = (size_t)gridDim.x * blockDim.x;
    for (size_t i = (size_t)blockIdx.x * blockDim.x + threadIdx.x;
         i < NX8 + NW8; i += stride) {
        const float* src;
        bf16* dst;
        if (i < NX8) { src = x + i * 8;          dst = xb + i * 8; }
        else         { src = w + (i - NX8) * 8;  dst = wb + (i - NX8) * 8; }
        f32x4 v0 = *(const f32x4*)(src);
        f32x4 v1 = *(const f32x4*)(src + 4);
        bf16x8 h;
        #pragma unroll
        for (int j = 0; j < 4; ++j) { h[j] = (bf16)v0[j]; h[4 + j] = (bf16)v1[j]; }
        *(bf16x8*)dst = h;   // 16B store
    }
}

// ---------------- Phase 2: m97-structure bf16 grouped GEMM -----------------
// 128x128 C tile, BK=32, global_load_lds width=16 staging, 4 waves each
// owning a 64x64 quadrant as 4x4 grid of 16x16x32 bf16 MFMAs.
__global__ __launch_bounds__(NTHREADS)
void grouped_gemm_bf16(const bf16* __restrict__ x,
                       const bf16* __restrict__ wgt,
                       const int*  __restrict__ seg_lens,
                       float* __restrict__ out)
{
    __shared__ __align__(16) bf16 As[BM * BK];
    __shared__ __align__(16) bf16 Bs[BN * BK];

    const int m    = blockIdx.y;          // row-tile slot
    const int col0 = blockIdx.x * BN;     // output-feature tile

    int e_sel = -1, row0 = 0, rows = 0;
    {
        int start = 0, acct = 0;
        #pragma unroll
        for (int e = 0; e < NE; ++e) {
            int len = seg_lens[e];
            int nt  = (len + BM - 1) >> 7;
            if (e_sel < 0 && m >= acct && m < acct + nt) {
                e_sel = e;
                row0  = start + (m - acct) * BM;
                int rem = start + len - row0;
                rows = rem < BM ? rem : BM;
            }
            acct  += nt;
            start += len;
        }
    }
    if (e_sel < 0) return;   // surplus slot (block-uniform, before any barrier)

    const int tid  = threadIdx.x;
    const int lane = tid & 63;
    const int wave = tid >> 6;
    const int wm   = (wave >> 1) * 64;
    const int wn   = (wave & 1) * 64;
    const int quad = lane >> 4;
    const int l16  = lane & 15;

    const bf16* wbase = wgt + ((size_t)e_sel * OUT_F + (size_t)col0) * IN_F;

    f32x4 acc[4][4] = {};

    for (int k0 = 0; k0 < IN_F; k0 += BK) {
        __syncthreads();  // previous iteration's ds_reads done before restage

        // ---- stage A tile (128 rows x 32 k bf16): 512 x 16B chunks, 2/thread
        #pragma unroll
        for (int t = 0; t < 2; ++t) {
            int c  = t * NTHREADS + tid;       // row = c>>2, kq = c&3
            int rg = row0 + (c >> 2);
            if (rg > T_TOK - 1) rg = T_TOK - 1;   // clamp partial last tile
            const bf16* gp = x + (size_t)rg * IN_F + k0 + (c & 3) * 8;
            __builtin_amdgcn_global_load_lds(
                (const __attribute__((address_space(1))) void*)gp,
                (__attribute__((address_space(3))) void*)(&As[c * 8]),
                16, 0, 0);
        }
        // ---- stage B tile (128 out-cols x 32 k bf16), trans_b: k-contiguous
        #pragma unroll
        for (int t = 0; t < 2; ++t) {
            int c = t * NTHREADS + tid;
            const bf16* gp = wbase + (size_t)(c >> 2) * IN_F + k0 + (c & 3) * 8;
            __builtin_amdgcn_global_load_lds(
                (const __attribute__((address_space(1))) void*)gp,
                (__attribute__((address_space(3))) void*)(&Bs[c * 8]),
                16, 0, 0);
        }
        __syncthreads();  // staging drained

        // ---- fragments: A[m=l16][k=quad*8+j], B[n=l16][k=quad*8+j] ----
        bf16x8 af[4], bfr[4];
        #pragma unroll
        for (int t = 0; t < 4; ++t)
            af[t] = *(const bf16x8*)(&As[(wm + t * 16 + l16) * BK + quad * 8]);
        #pragma unroll
        for (int u = 0; u < 4; ++u)
            bfr[u] = *(const bf16x8*)(&Bs[(wn + u * 16 + l16) * BK + quad * 8]);

        #pragma unroll
        for (int t = 0; t < 4; ++t)
            #pragma unroll
            for (int u = 0; u < 4; ++u)
                acc[t][u] = __builtin_amdgcn_mfma_f32_16x16x32_bf16(
                    af[t], bfr[u], acc[t][u], 0, 0, 0);
    }

    // ---- epilogue: C/D layout col=lane&15, row=quad*4+reg (m89/m91) ----
    #pragma unroll
    for (int t = 0; t < 4; ++t) {
        #pragma unroll
        for (int r = 0; r < 4; ++r) {
            int row = wm + t * 16 + quad * 4 + r;
            if (row < rows) {
                size_t ob = (size_t)(row0 + row) * OUT_F + col0;
                #pragma unroll
                for (int u = 0; u < 4; ++u)
                    out[ob + wn + u * 16 + l16] = acc[t][u][r];
            }
        }
    }
}

// ---------------- Fallback: round-3 fused kernel (if ws too small) ---------
__global__ __launch_bounds__(NTHREADS)
void grouped_gemm_f32io_fused(const float* __restrict__ x,
                              const float* __restrict__ wgt,
                              const int*  __restrict__ seg_lens,
                              float* __restrict__ out)
{
    __shared__ __align__(16) bf16 As[BM * BK];
    __shared__ __align__(16) bf16 Bs[BN * BK];

    const int m    = blockIdx.y;
    const int col0 = blockIdx.x * BN;

    int e_sel = -1, row0 = 0, rows = 0;
    {
        int start = 0, acct = 0;
        #pragma unroll
        for (int e = 0; e < NE; ++e) {
            int len = seg_lens[e];
            int nt  = (len + BM - 1) >> 7;
            if (e_sel < 0 && m >= acct && m < acct + nt) {
                e_sel = e;
                row0  = start + (m - acct) * BM;
                int rem = start + len - row0;
                rows = rem < BM ? rem : BM;
            }
            acct  += nt;
            start += len;
        }
    }
    if (e_sel < 0) return;

    const int tid  = threadIdx.x;
    const int lane = tid & 63;
    const int wave = tid >> 6;
    const int wm   = (wave >> 1) * 64;
    const int wn   = (wave & 1) * 64;
    const int quad = lane >> 4;
    const int l16  = lane & 15;

    const float* wbase = wgt + ((size_t)e_sel * OUT_F + (size_t)col0) * IN_F;

    f32x4 acc[4][4] = {};

    for (int k0 = 0; k0 < IN_F; k0 += BK) {
        f32x4 a_st[4], b_st[4];
        #pragma unroll
        for (int t = 0; t < 4; ++t) {
            int c  = t * NTHREADS + tid;
            int rg = row0 + (c >> 3);
            if (rg > T_TOK - 1) rg = T_TOK - 1;
            a_st[t] = *(const f32x4*)(x + (size_t)rg * IN_F + k0 + (c & 7) * 4);
            b_st[t] = *(const f32x4*)(wbase + (size_t)(c >> 3) * IN_F + k0 + (c & 7) * 4);
        }
        __syncthreads();
        #pragma unroll
        for (int t = 0; t < 4; ++t) {
            int c = t * NTHREADS + tid;
            bf16x4 ha, hb;
            #pragma unroll
            for (int j = 0; j < 4; ++j) { ha[j] = (bf16)a_st[t][j]; hb[j] = (bf16)b_st[t][j]; }
            *(bf16x4*)(&As[(c >> 3) * BK + (c & 7) * 4]) = ha;
            *(bf16x4*)(&Bs[(c >> 3) * BK + (c & 7) * 4]) = hb;
        }
        __syncthreads();

        bf16x8 af[4], bfr[4];
        #pragma unroll
        for (int t = 0; t < 4; ++t)
            af[t] = *(const bf16x8*)(&As[(wm + t * 16 + l16) * BK + quad * 8]);
        #pragma unroll
        for (int u = 0; u < 4; ++u)
            bfr[u] = *(const bf16x8*)(&Bs[(wn + u * 16 + l16) * BK + quad * 8]);

        #pragma unroll
        for (int t = 0; t < 4; ++t)
            #pragma unroll
            for (int u = 0; u < 4; ++u)
                acc[t][u] = __builtin_amdgcn_mfma_f32_16x16x32_bf16(
                    af[t], bfr[u], acc[t][u], 0, 0, 0);
    }

    #pragma unroll
    for (int t = 0; t < 4; ++t) {
        #pragma unroll
        for (int r = 0; r < 4; ++r) {
            int row = wm + t * 16 + quad * 4 + r;
            if (row < rows) {
                size_t ob = (size_t)(row0 + row) * OUT_F + col0;
                #pragma unroll
                for (int u = 0; u < 4; ++u)
                    out[ob + wn + u * 16 + l16] = acc[t][u][r];
            }
        }
    }
}

extern "C" void kernel_launch(void* const* d_in, const int* in_sizes, int n_in,
                              void* d_out, int out_size, void* d_ws, size_t ws_size,
                              hipStream_t stream) {
    const float* x   = (const float*)d_in[0];
    const float* wgt = (const float*)d_in[1];
    const int*   seg = (const int*)d_in[2];
    float* out = (float*)d_out;

    dim3 block(NTHREADS, 1, 1);
    dim3 grid2(OUT_F / BN, ROW_TILE_SLOTS, 1);

    if (ws_size >= WS_NEED) {
        bf16* xb = (bf16*)d_ws;
        bf16* wb = xb + NX_ELEM;
        // Phase 1: fp32 -> bf16 (memory-bound, ~144 MB moved)
        cvt_to_bf16<<<3072, block, 0, stream>>>(x, wgt, xb, wb);
        // Phase 2: bf16 MFMA GEMM with global_load_lds staging
        grouped_gemm_bf16<<<grid2, block, 0, stream>>>(xb, wb, seg, out);
    } else {
        grouped_gemm_f32io_fused<<<grid2, block, 0, stream>>>(x, wgt, seg, out);
    }
}